// Round 12
// baseline (620.114 us; speedup 1.0000x reference)
//
#include <hip/hip_runtime.h>
#include <hip/hip_cooperative_groups.h>
#include <hip/hip_bf16.h>
#include <stdint.h>

namespace cg = cooperative_groups;

#define H_DIM 1024
#define S_DIM 4096
#define B_DIM 4

typedef __bf16 bf16x8 __attribute__((ext_vector_type(8)));
typedef float f32x4 __attribute__((ext_vector_type(4)));
typedef unsigned short u16x4 __attribute__((ext_vector_type(4)));
typedef unsigned short u16x8 __attribute__((ext_vector_type(8)));

__device__ __forceinline__ unsigned short f2bf(float f) {
    union { float f; uint32_t u; } v; v.f = f;
    uint32_t u = v.u;
    uint32_t r = (u + 0x7FFFu + ((u >> 16) & 1u)) >> 16;  // round-to-nearest-even
    return (unsigned short)r;
}
__device__ __forceinline__ float bf2f(unsigned short u) {
    union { uint32_t u; float f; } v; v.u = (uint32_t)u << 16; return v.f;
}

// Clobber-free sync (R7): no "memory" clobber -> no compiler-inserted drains.
__device__ __forceinline__ void gate_vmcnt4() {
    __builtin_amdgcn_sched_barrier(0);
    asm volatile("s_waitcnt vmcnt(4)");
    __builtin_amdgcn_sched_barrier(0);
}
__device__ __forceinline__ void gate_vmcnt0() {
    __builtin_amdgcn_sched_barrier(0);
    asm volatile("s_waitcnt vmcnt(0)");
    __builtin_amdgcn_sched_barrier(0);
}
__device__ __forceinline__ void gate_lgkm0() {
    asm volatile("s_waitcnt lgkmcnt(0)");
    __builtin_amdgcn_sched_barrier(0);   // rule #18
}

template <int IMM>
__device__ __forceinline__ bf16x8 ds_read_b128_imm(unsigned addr) {
    bf16x8 r;
    asm volatile("ds_read_b128 %0, %1 offset:%2"
                 : "=v"(r) : "v"(addr), "i"(IMM));
    return r;
}

// ============================================================================
// R8's proven GEMM body (coalesced slot-permuted staging, BK=64, 4-phase,
// clobber-free counted-vmcnt gates) as a device function for the fused
// cooperative kernel. bx/by/bz_raw replace blockIdx.{x,y,z}.
// C[M,N] = A[M,K] @ Bt[N,K]^T. 256x256 tile, 8 waves (2Mx4N), wave 128x64.
// LDS: [buf(2)][A 32KB | B 32KB] = 131072 B. Gate audit as R8 (verified).
// Ends fully drained (tail vmcnt(0)) + __syncthreads around epilogue overlay.
// ============================================================================
template <typename OutT, int NSPLIT>
__device__ __forceinline__ void gemm_body(
    const unsigned short* __restrict__ A,
    const unsigned short* __restrict__ Bt,
    OutT* __restrict__ C,
    int K, int lda, int ldb, int ldc,
    size_t sA, size_t sB, size_t sC, size_t sSplit,
    int bx, int by, int bz_raw) {
    extern __shared__ char smem_raw[];

    const int tid  = threadIdx.x;
    const int w    = tid >> 6;       // 0..7
    const int lane = tid & 63;
    const int wm   = w & 1;
    const int wn   = w >> 1;
    const int q    = lane >> 4;
    const int col  = lane & 15;

    const int tileM = bx * 256;
    const int tileN = by * 256;
    const int bz   = bz_raw / NSPLIT;
    const int sp   = bz_raw % NSPLIT;
    const int Ksub = K / NSPLIT;
    const int T    = Ksub >> 6;      // K-tiles of 64

    const unsigned short* Ab = A + sA * bz + (size_t)sp * Ksub;
    const unsigned short* Bb = Bt + sB * bz + (size_t)sp * Ksub;

    auto lds3 = (__attribute__((address_space(3))) char*)&smem_raw[0];
    const unsigned ldsBase = (unsigned)(size_t)lds3;

    // fragment read bases: element (row, k=q*8+e) at byte row*64 + slot*16,
    // slot = q ^ ((row>>1)&3) = q ^ ((col>>1)&3)
    const int slot = q ^ ((col >> 1) & 3);
    const unsigned aBase = ldsBase + (unsigned)(wm * 8192 + col * 64 + slot * 16);
    const unsigned bBase = ldsBase + 32768u + (unsigned)(wn * 4096 + col * 64 + slot * 16);

    // coalesced staging: wave w unit j -> rowgroup g=2w+j (16 rows x 64B);
    // lane l -> row l>>2, k8-chunk (l&3)^((l>>3)&3); 4-lane groups = 1 line.
    const int lrow = lane >> 2;
    const int koff = ((lane & 3) ^ ((lane >> 3) & 3)) * 8;
    const unsigned short* pA[2];
    const unsigned short* pB[2];
    unsigned dstR[2];
#pragma unroll
    for (int j = 0; j < 2; ++j) {
        int g = 2 * w + j;
        pA[j] = Ab + (size_t)(tileM + g * 16 + lrow) * lda + koff;
        pB[j] = Bb + (size_t)(tileN + g * 16 + lrow) * ldb + koff;
        dstR[j] = (unsigned)(g * 1024);
    }
    auto stageA = [&](int tgt, int h) {
#pragma unroll
        for (int j = 0; j < 2; ++j)
            __builtin_amdgcn_global_load_lds(
                (const __attribute__((address_space(1))) void*)(pA[j] + tgt * 64 + h * 32),
                (__attribute__((address_space(3))) void*)(lds3 + ((unsigned)(tgt & 1) * 65536u + (unsigned)h * 16384u + dstR[j])),
                16, 0, 0);
    };
    auto stageB = [&](int tgt, int h) {
#pragma unroll
        for (int j = 0; j < 2; ++j)
            __builtin_amdgcn_global_load_lds(
                (const __attribute__((address_space(1))) void*)(pB[j] + tgt * 64 + h * 32),
                (__attribute__((address_space(3))) void*)(lds3 + ((unsigned)(tgt & 1) * 65536u + 32768u + (unsigned)h * 16384u + dstR[j])),
                16, 0, 0);
    };

    f32x4 acc[8][4];
#pragma unroll
    for (int r = 0; r < 8; ++r)
#pragma unroll
        for (int c = 0; c < 4; ++c)
            acc[r][c] = (f32x4){0.f, 0.f, 0.f, 0.f};

    // prologue: tile 0's halves in consumption order A0,B0,A1,B1
    stageA(0, 0); stageB(0, 0); stageA(0, 1); stageB(0, 1);

    for (int n = 0; n < T; ++n) {
        const unsigned aAddr = aBase + (unsigned)((n & 1) << 16);
        const unsigned bAddr = bBase + (unsigned)((n & 1) << 16);
        const bool pf = (n + 1 < T);
        bf16x8 av[4], bv[4];

        // ===== G0: A(n,0),B(n,0) landed; A(n,1),B(n,1) stay in flight =====
        gate_vmcnt4();
        __builtin_amdgcn_s_barrier();

        // ---- P0: kc=0, mf 0..3 ----
        av[0] = ds_read_b128_imm<0>(aAddr);
        av[1] = ds_read_b128_imm<1024>(aAddr);
        av[2] = ds_read_b128_imm<2048>(aAddr);
        av[3] = ds_read_b128_imm<3072>(aAddr);
        bv[0] = ds_read_b128_imm<0>(bAddr);
        bv[1] = ds_read_b128_imm<1024>(bAddr);
        bv[2] = ds_read_b128_imm<2048>(bAddr);
        bv[3] = ds_read_b128_imm<3072>(bAddr);
        if (pf) stageA(n + 1, 0);
        gate_lgkm0();
        __builtin_amdgcn_s_setprio(1);
#pragma unroll
        for (int mf = 0; mf < 4; ++mf)
#pragma unroll
            for (int nf = 0; nf < 4; ++nf)
                acc[mf][nf] = __builtin_amdgcn_mfma_f32_16x16x32_bf16(
                    av[mf], bv[nf], acc[mf][nf], 0, 0, 0);
        __builtin_amdgcn_s_setprio(0);

        // ---- P1: kc=0, mf 4..7 (bv reused) ----
        av[0] = ds_read_b128_imm<4096>(aAddr);
        av[1] = ds_read_b128_imm<5120>(aAddr);
        av[2] = ds_read_b128_imm<6144>(aAddr);
        av[3] = ds_read_b128_imm<7168>(aAddr);
        if (pf) stageB(n + 1, 0);
        gate_lgkm0();
        __builtin_amdgcn_s_setprio(1);
#pragma unroll
        for (int mf = 0; mf < 4; ++mf)
#pragma unroll
            for (int nf = 0; nf < 4; ++nf)
                acc[4 + mf][nf] = __builtin_amdgcn_mfma_f32_16x16x32_bf16(
                    av[mf], bv[nf], acc[4 + mf][nf], 0, 0, 0);
        __builtin_amdgcn_s_setprio(0);

        // ===== G1: A(n,1),B(n,1) landed; n+1's first halves in flight =====
        if (pf) gate_vmcnt4();
        else    gate_vmcnt0();
        __builtin_amdgcn_s_barrier();

        // ---- P2: kc=1, mf 0..3, new bv ----
        av[0] = ds_read_b128_imm<16384 + 0>(aAddr);
        av[1] = ds_read_b128_imm<16384 + 1024>(aAddr);
        av[2] = ds_read_b128_imm<16384 + 2048>(aAddr);
        av[3] = ds_read_b128_imm<16384 + 3072>(aAddr);
        bv[0] = ds_read_b128_imm<16384 + 0>(bAddr);
        bv[1] = ds_read_b128_imm<16384 + 1024>(bAddr);
        bv[2] = ds_read_b128_imm<16384 + 2048>(bAddr);
        bv[3] = ds_read_b128_imm<16384 + 3072>(bAddr);
        if (pf) stageA(n + 1, 1);
        gate_lgkm0();
        __builtin_amdgcn_s_setprio(1);
#pragma unroll
        for (int mf = 0; mf < 4; ++mf)
#pragma unroll
            for (int nf = 0; nf < 4; ++nf)
                acc[mf][nf] = __builtin_amdgcn_mfma_f32_16x16x32_bf16(
                    av[mf], bv[nf], acc[mf][nf], 0, 0, 0);
        __builtin_amdgcn_s_setprio(0);

        // ---- P3: kc=1, mf 4..7 ----
        av[0] = ds_read_b128_imm<16384 + 4096>(aAddr);
        av[1] = ds_read_b128_imm<16384 + 5120>(aAddr);
        av[2] = ds_read_b128_imm<16384 + 6144>(aAddr);
        av[3] = ds_read_b128_imm<16384 + 7168>(aAddr);
        if (pf) stageB(n + 1, 1);
        gate_lgkm0();
        __builtin_amdgcn_s_setprio(1);
#pragma unroll
        for (int mf = 0; mf < 4; ++mf)
#pragma unroll
            for (int nf = 0; nf < 4; ++nf)
                acc[4 + mf][nf] = __builtin_amdgcn_mfma_f32_16x16x32_bf16(
                    av[mf], bv[nf], acc[4 + mf][nf], 0, 0, 0);
        __builtin_amdgcn_s_setprio(0);
    }

    // epilogue: per-wave LDS transpose (stride 68 floats), coalesced stores.
    OutT* Cb = C + sC * bz + sSplit * sp;
    __syncthreads();   // full drain; epi overlays stage region
    float* lws = (float*)(smem_raw) + (size_t)w * 1088;
    const int lr = lane >> 4;
    const int lc = lane & 15;
#pragma unroll
    for (int mf = 0; mf < 8; ++mf) {
#pragma unroll
        for (int nf = 0; nf < 4; ++nf)
#pragma unroll
            for (int v = 0; v < 4; ++v)
                lws[(q * 4 + v) * 68 + nf * 16 + col] = acc[mf][nf][v];
#pragma unroll
        for (int p = 0; p < 4; ++p) {
            f32x4 t = *(const f32x4*)&lws[(p * 4 + lr) * 68 + lc * 4];
            int row  = tileM + wm * 128 + mf * 16 + p * 4 + lr;
            int colg = tileN + wn * 64 + lc * 4;
            if constexpr (sizeof(OutT) == 2) {
                u16x4 u;
                u[0] = f2bf(t[0]); u[1] = f2bf(t[1]);
                u[2] = f2bf(t[2]); u[3] = f2bf(t[3]);
                *(u16x4*)&Cb[(size_t)row * ldc + colg] = u;
            } else {
                *(f32x4*)&Cb[(size_t)row * ldc + colg] = t;
            }
        }
    }
    __syncthreads();   // epi LDS reads done before next phase reuses smem
}

// Sum NSPLIT bf16 partial slices -> bf16, grid-strided over 256x512 threads.
template <int NSPLIT>
__device__ __forceinline__ void reduce_body(const unsigned short* __restrict__ P,
                                            unsigned short* __restrict__ Out,
                                            size_t sSplit, int bid, int tid) {
#pragma unroll
    for (int it = 0; it < 4; ++it) {
        size_t i = ((size_t)(it * 131072 + bid * 512 + tid)) * 8;
        float s[8] = {0.f, 0.f, 0.f, 0.f, 0.f, 0.f, 0.f, 0.f};
#pragma unroll
        for (int sp = 0; sp < NSPLIT; ++sp) {
            u16x8 u = *(const u16x8*)&P[(size_t)sp * sSplit + i];
#pragma unroll
            for (int k = 0; k < 8; ++k) s[k] += bf2f(u[k]);
        }
        u16x8 o;
#pragma unroll
        for (int k = 0; k < 8; ++k) o[k] = f2bf(s[k]);
        *(u16x8*)&Out[i] = o;
    }
}

// 64x64 fp32->bf16 cast tile with LDS transpose (f32 [64][65], 512 threads).
// DUAL=true also writes the non-transposed bf16 copy (Xb).
template <bool DUAL>
__device__ __forceinline__ void cast_tile(const float* __restrict__ src, int lds_,
                                          unsigned short* __restrict__ dstN,
                                          unsigned short* __restrict__ dstT, int ldt,
                                          int tid) {
    extern __shared__ char smem_raw[];
    float* tile = (float*)smem_raw;          // [64][65]
    const int tx = tid & 15;
    const int ty = tid >> 4;                 // 0..31
#pragma unroll
    for (int jj = 0; jj < 2; ++jj) {
        int s = ty + 32 * jj;
        f32x4 v = *(const f32x4*)&src[(size_t)s * lds_ + tx * 4];
        u16x4 o;
#pragma unroll
        for (int k = 0; k < 4; ++k) {
            tile[s * 65 + tx * 4 + k] = v[k];
            o[k] = f2bf(v[k]);
        }
        if constexpr (DUAL)
            *(u16x4*)&dstN[(size_t)s * lds_ + tx * 4] = o;
    }
    __syncthreads();
#pragma unroll
    for (int jj = 0; jj < 2; ++jj) {
        int hh = ty + 32 * jj;
        u16x4 o;
#pragma unroll
        for (int k = 0; k < 4; ++k)
            o[k] = f2bf(tile[(tx * 4 + k) * 65 + hh]);
        *(u16x4*)&dstT[(size_t)hh * ldt + tx * 4] = o;
    }
    __syncthreads();
}

// ============================================================================
// R12 (R11 compile-fixed): FUSED COOPERATIVE PIPELINE — one persistent kernel,
// 256 blocks x 512 threads x 128KB LDS (1 block/CU, coop co-residency),
// grid.sync between phases. Eliminates the ~85 µs of inter-dispatch overhead
// (budget analysis: total ≈ 142 + gemm2 + gemm4 across R3/R5/R8, but kernel
// work sums to ~140). Phases (each uniform-work across exactly 256 blocks):
//   A: cast W (1 tile/blk) + cast X -> Xb,XT (16 tiles/blk)
//   B: gemm2  Gpart = XT @ XT^T    (split-K=4, bid -> (4,4,16))
//   C: reduce1 Gpart -> G
//   D: gemm3  MTpart = G @ WT^T    (split-K=4)
//   E: reduce2 MTpart -> MT
//   F: gemm4  out = Xb @ MT^T      (bid -> (16,4,4), fp32 out)
// __threadfence() before each grid.sync (cross-XCD visibility); all LDS-DMA
// drained (tail vmcnt(0)) and __syncthreads'd before each phase boundary.
// ============================================================================
__global__ __launch_bounds__(512, 2)
void mega_kernel(const float* __restrict__ X, const float* __restrict__ W,
                 float* __restrict__ out, char* __restrict__ ws) {
    cg::grid_group grid = cg::this_grid();
    const int bid = blockIdx.x;
    const int tid = threadIdx.x;

    unsigned short* Xb = (unsigned short*)(ws);              // [b][s][h]
    unsigned short* XT = (unsigned short*)(ws + 33554432);   // [b][h][s]
    unsigned short* WT = (unsigned short*)(ws + 67108864);   // [h'][o]
    unsigned short* G  = (unsigned short*)(ws + 69206016);   // [b][o][h]
    unsigned short* MT = (unsigned short*)(ws + 77594624);   // [b][o][o']
    unsigned short* Gpart  = (unsigned short*)(ws + 85983232);
    unsigned short* MTpart = (unsigned short*)(ws + 85983232);  // reused
    const size_t sBH = (size_t)B_DIM * H_DIM * H_DIM;

    // ---- Phase A: casts ----
    {
        // cast_w: tile (o0,b0); WT[b0+c][o0+r] = W[o0+r][b0+c]
        const int o0 = (bid & 15) * 64, b0 = (bid >> 4) * 64;
        cast_tile<false>(W + (size_t)o0 * H_DIM + b0, H_DIM,
                         nullptr,
                         WT + (size_t)b0 * H_DIM + o0, H_DIM, tid);
        // cast_x: 16 tiles/block
        for (int i = 0; i < 16; ++i) {
            int t = bid * 16 + i;
            int b = t >> 10;
            int rem = t & 1023;
            int h0 = (rem & 15) * 64, s0 = (rem >> 4) * 64;
            cast_tile<true>(X + ((size_t)b * S_DIM + s0) * H_DIM + h0, H_DIM,
                            Xb + ((size_t)b * S_DIM + s0) * H_DIM + h0,
                            XT + ((size_t)b * H_DIM + h0) * S_DIM + s0, S_DIM, tid);
        }
    }
    __threadfence();
    grid.sync();

    // ---- Phase B: gemm2 (grid (4,4,16)) ----
    gemm_body<unsigned short, 4>(XT, XT, Gpart,
        S_DIM, S_DIM, S_DIM, H_DIM,
        (size_t)H_DIM * S_DIM, (size_t)H_DIM * S_DIM, (size_t)H_DIM * H_DIM, sBH,
        bid & 3, (bid >> 2) & 3, bid >> 4);
    __threadfence();
    grid.sync();

    // ---- Phase C: reduce1 ----
    reduce_body<4>(Gpart, G, sBH, bid, tid);
    __threadfence();
    grid.sync();

    // ---- Phase D: gemm3 (grid (4,4,16)) ----
    gemm_body<unsigned short, 4>(G, WT, MTpart,
        H_DIM, H_DIM, H_DIM, H_DIM,
        (size_t)H_DIM * H_DIM, (size_t)0, (size_t)H_DIM * H_DIM, sBH,
        bid & 3, (bid >> 2) & 3, bid >> 4);
    __threadfence();
    grid.sync();

    // ---- Phase E: reduce2 ----
    reduce_body<4>(MTpart, MT, sBH, bid, tid);
    __threadfence();
    grid.sync();

    // ---- Phase F: gemm4 (grid (16,4,4), fp32 out) ----
    gemm_body<float, 1>(Xb, MT, out,
        H_DIM, H_DIM, H_DIM, H_DIM,
        (size_t)S_DIM * H_DIM, (size_t)H_DIM * H_DIM, (size_t)S_DIM * H_DIM, 0,
        bid & 15, (bid >> 4) & 3, bid >> 6);
}

extern "C" void kernel_launch(void* const* d_in, const int* in_sizes, int n_in,
                              void* d_out, int out_size, void* d_ws, size_t ws_size,
                              hipStream_t stream) {
    const float* X = (const float*)d_in[0];   // [4,4096,1024]
    const float* W = (const float*)d_in[1];   // [1024,1024]
    float* out = (float*)d_out;               // [4,4096,1024] fp32
    char* ws = (char*)d_ws;
    // workspace high-water: 102,760,448 bytes < 153,092,096 proven available

    void* args[] = {(void*)&X, (void*)&W, (void*)&out, (void*)&ws};
    (void)hipLaunchCooperativeKernel((const void*)mega_kernel,
                                     dim3(256), dim3(512), args, 131072, stream);
}

// Round 13
// 229.604 us; speedup vs baseline: 2.7008x; 2.7008x over previous
//
#include <hip/hip_runtime.h>
#include <hip/hip_bf16.h>
#include <stdint.h>

#define H_DIM 1024
#define S_DIM 4096
#define B_DIM 4

typedef __bf16 bf16x8 __attribute__((ext_vector_type(8)));
typedef float f32x4 __attribute__((ext_vector_type(4)));
typedef unsigned short u16x4 __attribute__((ext_vector_type(4)));
typedef unsigned short u16x8 __attribute__((ext_vector_type(8)));

__device__ __forceinline__ unsigned short f2bf(float f) {
    union { float f; uint32_t u; } v; v.f = f;
    uint32_t u = v.u;
    uint32_t r = (u + 0x7FFFu + ((u >> 16) & 1u)) >> 16;  // round-to-nearest-even
    return (unsigned short)r;
}
__device__ __forceinline__ float bf2f(unsigned short u) {
    union { uint32_t u; float f; } v; v.u = (uint32_t)u << 16; return v.f;
}

// Clobber-free sync (R7): no "memory" clobber -> no compiler-inserted drains.
__device__ __forceinline__ void gate_vmcnt4() {
    __builtin_amdgcn_sched_barrier(0);
    asm volatile("s_waitcnt vmcnt(4)");
    __builtin_amdgcn_sched_barrier(0);
}
__device__ __forceinline__ void gate_vmcnt0() {
    __builtin_amdgcn_sched_barrier(0);
    asm volatile("s_waitcnt vmcnt(0)");
    __builtin_amdgcn_sched_barrier(0);
}
__device__ __forceinline__ void gate_lgkm0() {
    asm volatile("s_waitcnt lgkmcnt(0)");
    __builtin_amdgcn_sched_barrier(0);   // rule #18
}

template <int IMM>
__device__ __forceinline__ bf16x8 ds_read_b128_imm(unsigned addr) {
    bf16x8 r;
    asm volatile("ds_read_b128 %0, %1 offset:%2"
                 : "=v"(r) : "v"(addr), "i"(IMM));
    return r;
}

// R13: cast_x + cast_w merged. z<4: X[b][s][h] fp32 -> Xb bf16 and XT bf16.
// z==4: W[o][h'] fp32 -> WT[h'][o] bf16 (y<16 only; 64x64 tiles).
__global__ __launch_bounds__(256)
void cast_xw_kernel(const float* __restrict__ X,
                    const float* __restrict__ W,
                    unsigned short* __restrict__ Xb,
                    unsigned short* __restrict__ XT,
                    unsigned short* __restrict__ WT) {
    __shared__ float tile[64][65];
    const int tx = threadIdx.x;   // 0..15
    const int ty = threadIdx.y;   // 0..15
    const int z  = blockIdx.z;

    if (z == 4) {
        // ---- W cast: o0 rows, b0 cols; WT[b0+c][o0+r] = W[o0+r][b0+c] ----
        if (blockIdx.y >= 16) return;
        const int o0 = blockIdx.x * 64;
        const int b0 = blockIdx.y * 64;
#pragma unroll
        for (int j = 0; j < 4; ++j) {
            int o = ty + 16 * j;
            f32x4 v = *(const f32x4*)&W[(size_t)(o0 + o) * H_DIM + b0 + tx * 4];
#pragma unroll
            for (int k = 0; k < 4; ++k)
                tile[o][tx * 4 + k] = v[k];
        }
        __syncthreads();
#pragma unroll
        for (int j = 0; j < 4; ++j) {
            int hh = ty + 16 * j;
            u16x4 o;
#pragma unroll
            for (int k = 0; k < 4; ++k)
                o[k] = f2bf(tile[tx * 4 + k][hh]);
            *(u16x4*)&WT[(size_t)(b0 + hh) * H_DIM + o0 + tx * 4] = o;
        }
        return;
    }

    // ---- X cast (R8-identical) ----
    const int b  = z;
    const int h0 = blockIdx.x * 64;
    const int s0 = blockIdx.y * 64;
#pragma unroll
    for (int j = 0; j < 4; ++j) {
        int s = ty + 16 * j;
        f32x4 v = *(const f32x4*)&X[((size_t)b * S_DIM + s0 + s) * H_DIM + h0 + tx * 4];
        u16x4 o;
#pragma unroll
        for (int k = 0; k < 4; ++k) {
            tile[s][tx * 4 + k] = v[k];
            o[k] = f2bf(v[k]);
        }
        *(u16x4*)&Xb[((size_t)b * S_DIM + s0 + s) * H_DIM + h0 + tx * 4] = o;
    }
    __syncthreads();
#pragma unroll
    for (int j = 0; j < 4; ++j) {
        int hh = ty + 16 * j;
        u16x4 o;
#pragma unroll
        for (int k = 0; k < 4; ++k)
            o[k] = f2bf(tile[tx * 4 + k][hh]);
        *(u16x4*)&XT[((size_t)b * H_DIM + h0 + hh) * S_DIM + s0 + tx * 4] = o;
    }
}

// Sum NSPLIT bf16 partials -> bf16. 16B/lane both directions.
template <int NSPLIT>
__global__ void reduce_cast_u16_kernel(const unsigned short* __restrict__ P,
                                       unsigned short* __restrict__ Out,
                                       size_t sSplit) {
    size_t i = ((size_t)blockIdx.x * blockDim.x + threadIdx.x) * 8;
    float s[8] = {0.f, 0.f, 0.f, 0.f, 0.f, 0.f, 0.f, 0.f};
#pragma unroll
    for (int sp = 0; sp < NSPLIT; ++sp) {
        u16x8 u = *(const u16x8*)&P[(size_t)sp * sSplit + i];
#pragma unroll
        for (int k = 0; k < 8; ++k) s[k] += bf2f(u[k]);
    }
    u16x8 o;
#pragma unroll
    for (int k = 0; k < 8; ++k) o[k] = f2bf(s[k]);
    *(u16x8*)&Out[i] = o;
}

// ============================================================================
// R8 GEMM (restored verbatim — session best, 43 µs/gemm ≈ 800 TF ≈ 94% of the
// m248 same-shape plain-HIP ceiling). C[M,N] = A[M,K] @ Bt[N,K]^T.
//
// COALESCED STAGING (the R8 win, +33%): LDS per operand [kc(2)][row(256)]
// [32k = 64B]. Staging wave-instr = 16 rows x 64B: lane l -> row l>>2,
// k8-chunk (l&3)^((l>>3)&3) (slot perm). 4 consecutive lanes = one fully-used
// 64B line = the 1024-line/K-tile coalescing minimum (fragment-major layout
// was 4096 = the R0-R7 schedule-invariant TA wall). LDS dest stays linear
// (rule #21: swizzle lives in the per-lane SOURCE address, m173).
// ds_read fragment (q,col): byte kc*16384 + row*64 + slot*16, slot =
// q^((col>>1)&3) — per-thread constant; 2-way bank alias = free (m136).
//
// Schedule per K-tile n (4-phase paced, clobber-free gates):
//   G0: vmcnt(4); s_barrier      [A(n,0),B(n,0) landed; (n,1) in flight]
//   P0: 8 ds_reads kc0 | stage A(n+1,0) | lgkm0 | prio1 16MFMA prio0
//   P1: 4 ds_reads kc0-hi | stage B(n+1,0) | lgkm0 | 16MFMA
//   G1: vmcnt(pf?4:0); s_barrier
//   P2/P3: kc1 mirror, staging A(n+1,1)/B(n+1,1)
// 2 loads/thread/stage-call; gates drain exactly the oldest 4. WAR: restage
// of buf (n+1)&1 only after G0/G1 barriers; all tile-(n-1) reads returned
// before each wave's own lgkm0 which precedes its barrier arrival.
// Requires M,N multiples of 256, T = Ksub/64 >= 1.
// ============================================================================
template <typename OutT, int NSPLIT>
__global__ __launch_bounds__(512, 2)
void gemm_c8_kernel(const unsigned short* __restrict__ A,
                    const unsigned short* __restrict__ Bt,
                    OutT* __restrict__ C,
                    int K, int lda, int ldb, int ldc,
                    size_t sA, size_t sB, size_t sC, size_t sSplit) {
    extern __shared__ char smem_raw[];
    // stage: [buf(2)][A 32KB | B 32KB] = 131072 B; epi overlays post-sync.

    const int tid  = threadIdx.x;
    const int w    = tid >> 6;       // 0..7
    const int lane = tid & 63;
    const int wm   = w & 1;          // M half: rows wm*128
    const int wn   = w >> 1;         // N quarter: cols wn*64
    const int q    = lane >> 4;      // 0..3 (k8 within kc-half)
    const int col  = lane & 15;

    const int tileM = blockIdx.x * 256;
    const int tileN = blockIdx.y * 256;
    const int bz   = blockIdx.z / NSPLIT;
    const int sp   = blockIdx.z % NSPLIT;
    const int Ksub = K / NSPLIT;
    const int T    = Ksub >> 6;      // K-tiles of 64

    const unsigned short* Ab = A + sA * bz + (size_t)sp * Ksub;
    const unsigned short* Bb = Bt + sB * bz + (size_t)sp * Ksub;

    auto lds3 = (__attribute__((address_space(3))) char*)&smem_raw[0];
    const unsigned ldsBase = (unsigned)(size_t)lds3;

    const int slot = q ^ ((col >> 1) & 3);
    const unsigned aBase = ldsBase + (unsigned)(wm * 8192 + col * 64 + slot * 16);
    const unsigned bBase = ldsBase + 32768u + (unsigned)(wn * 4096 + col * 64 + slot * 16);

    const int lrow = lane >> 2;
    const int koff = ((lane & 3) ^ ((lane >> 3) & 3)) * 8;
    const unsigned short* pA[2];
    const unsigned short* pB[2];
    unsigned dstR[2];
#pragma unroll
    for (int j = 0; j < 2; ++j) {
        int g = 2 * w + j;
        pA[j] = Ab + (size_t)(tileM + g * 16 + lrow) * lda + koff;
        pB[j] = Bb + (size_t)(tileN + g * 16 + lrow) * ldb + koff;
        dstR[j] = (unsigned)(g * 1024);
    }
    auto stageA = [&](int tgt, int h) {
#pragma unroll
        for (int j = 0; j < 2; ++j)
            __builtin_amdgcn_global_load_lds(
                (const __attribute__((address_space(1))) void*)(pA[j] + tgt * 64 + h * 32),
                (__attribute__((address_space(3))) void*)(lds3 + ((unsigned)(tgt & 1) * 65536u + (unsigned)h * 16384u + dstR[j])),
                16, 0, 0);
    };
    auto stageB = [&](int tgt, int h) {
#pragma unroll
        for (int j = 0; j < 2; ++j)
            __builtin_amdgcn_global_load_lds(
                (const __attribute__((address_space(1))) void*)(pB[j] + tgt * 64 + h * 32),
                (__attribute__((address_space(3))) void*)(lds3 + ((unsigned)(tgt & 1) * 65536u + 32768u + (unsigned)h * 16384u + dstR[j])),
                16, 0, 0);
    };

    f32x4 acc[8][4];
#pragma unroll
    for (int r = 0; r < 8; ++r)
#pragma unroll
        for (int c = 0; c < 4; ++c)
            acc[r][c] = (f32x4){0.f, 0.f, 0.f, 0.f};

    // prologue: tile 0's 4 halves, consumption order A0,B0,A1,B1
    stageA(0, 0); stageB(0, 0); stageA(0, 1); stageB(0, 1);

    for (int n = 0; n < T; ++n) {
        const unsigned aAddr = aBase + (unsigned)((n & 1) << 16);
        const unsigned bAddr = bBase + (unsigned)((n & 1) << 16);
        const bool pf = (n + 1 < T);
        bf16x8 av[4], bv[4];

        // ===== G0 =====
        gate_vmcnt4();
        __builtin_amdgcn_s_barrier();

        // ---- P0: kc=0, mf 0..3 ----
        av[0] = ds_read_b128_imm<0>(aAddr);
        av[1] = ds_read_b128_imm<1024>(aAddr);
        av[2] = ds_read_b128_imm<2048>(aAddr);
        av[3] = ds_read_b128_imm<3072>(aAddr);
        bv[0] = ds_read_b128_imm<0>(bAddr);
        bv[1] = ds_read_b128_imm<1024>(bAddr);
        bv[2] = ds_read_b128_imm<2048>(bAddr);
        bv[3] = ds_read_b128_imm<3072>(bAddr);
        if (pf) stageA(n + 1, 0);
        gate_lgkm0();
        __builtin_amdgcn_s_setprio(1);
#pragma unroll
        for (int mf = 0; mf < 4; ++mf)
#pragma unroll
            for (int nf = 0; nf < 4; ++nf)
                acc[mf][nf] = __builtin_amdgcn_mfma_f32_16x16x32_bf16(
                    av[mf], bv[nf], acc[mf][nf], 0, 0, 0);
        __builtin_amdgcn_s_setprio(0);

        // ---- P1: kc=0, mf 4..7 (bv reused) ----
        av[0] = ds_read_b128_imm<4096>(aAddr);
        av[1] = ds_read_b128_imm<5120>(aAddr);
        av[2] = ds_read_b128_imm<6144>(aAddr);
        av[3] = ds_read_b128_imm<7168>(aAddr);
        if (pf) stageB(n + 1, 0);
        gate_lgkm0();
        __builtin_amdgcn_s_setprio(1);
#pragma unroll
        for (int mf = 0; mf < 4; ++mf)
#pragma unroll
            for (int nf = 0; nf < 4; ++nf)
                acc[4 + mf][nf] = __builtin_amdgcn_mfma_f32_16x16x32_bf16(
                    av[mf], bv[nf], acc[4 + mf][nf], 0, 0, 0);
        __builtin_amdgcn_s_setprio(0);

        // ===== G1 =====
        if (pf) gate_vmcnt4();
        else    gate_vmcnt0();
        __builtin_amdgcn_s_barrier();

        // ---- P2: kc=1, mf 0..3, new bv ----
        av[0] = ds_read_b128_imm<16384 + 0>(aAddr);
        av[1] = ds_read_b128_imm<16384 + 1024>(aAddr);
        av[2] = ds_read_b128_imm<16384 + 2048>(aAddr);
        av[3] = ds_read_b128_imm<16384 + 3072>(aAddr);
        bv[0] = ds_read_b128_imm<16384 + 0>(bAddr);
        bv[1] = ds_read_b128_imm<16384 + 1024>(bAddr);
        bv[2] = ds_read_b128_imm<16384 + 2048>(bAddr);
        bv[3] = ds_read_b128_imm<16384 + 3072>(bAddr);
        if (pf) stageA(n + 1, 1);
        gate_lgkm0();
        __builtin_amdgcn_s_setprio(1);
#pragma unroll
        for (int mf = 0; mf < 4; ++mf)
#pragma unroll
            for (int nf = 0; nf < 4; ++nf)
                acc[mf][nf] = __builtin_amdgcn_mfma_f32_16x16x32_bf16(
                    av[mf], bv[nf], acc[mf][nf], 0, 0, 0);
        __builtin_amdgcn_s_setprio(0);

        // ---- P3: kc=1, mf 4..7 ----
        av[0] = ds_read_b128_imm<16384 + 4096>(aAddr);
        av[1] = ds_read_b128_imm<16384 + 5120>(aAddr);
        av[2] = ds_read_b128_imm<16384 + 6144>(aAddr);
        av[3] = ds_read_b128_imm<16384 + 7168>(aAddr);
        if (pf) stageB(n + 1, 1);
        gate_lgkm0();
        __builtin_amdgcn_s_setprio(1);
#pragma unroll
        for (int mf = 0; mf < 4; ++mf)
#pragma unroll
            for (int nf = 0; nf < 4; ++nf)
                acc[4 + mf][nf] = __builtin_amdgcn_mfma_f32_16x16x32_bf16(
                    av[mf], bv[nf], acc[4 + mf][nf], 0, 0, 0);
        __builtin_amdgcn_s_setprio(0);
    }

    // epilogue: per-wave LDS transpose (stride 68 floats), coalesced stores.
    OutT* Cb = C + sC * bz + sSplit * sp;
    __syncthreads();   // full drain once; epi overlays stage region
    float* lws = (float*)(smem_raw) + (size_t)w * 1088;
    const int lr = lane >> 4;
    const int lc = lane & 15;
#pragma unroll
    for (int mf = 0; mf < 8; ++mf) {
#pragma unroll
        for (int nf = 0; nf < 4; ++nf)
#pragma unroll
            for (int v = 0; v < 4; ++v)
                lws[(q * 4 + v) * 68 + nf * 16 + col] = acc[mf][nf][v];
#pragma unroll
        for (int p = 0; p < 4; ++p) {
            f32x4 t = *(const f32x4*)&lws[(p * 4 + lr) * 68 + lc * 4];
            int row  = tileM + wm * 128 + mf * 16 + p * 4 + lr;
            int colg = tileN + wn * 64 + lc * 4;
            if constexpr (sizeof(OutT) == 2) {
                u16x4 u;
                u[0] = f2bf(t[0]); u[1] = f2bf(t[1]);
                u[2] = f2bf(t[2]); u[3] = f2bf(t[3]);
                *(u16x4*)&Cb[(size_t)row * ldc + colg] = u;
            } else {
                *(f32x4*)&Cb[(size_t)row * ldc + colg] = t;
            }
        }
        // per-wave epi slice is private; no inter-mf barrier needed
    }
}

extern "C" void kernel_launch(void* const* d_in, const int* in_sizes, int n_in,
                              void* d_out, int out_size, void* d_ws, size_t ws_size,
                              hipStream_t stream) {
    const float* X = (const float*)d_in[0];   // [4,4096,1024]
    const float* W = (const float*)d_in[1];   // [1024,1024]
    float* out = (float*)d_out;               // [4,4096,1024] fp32

    char* ws = (char*)d_ws;
    unsigned short* Xb = (unsigned short*)(ws);              // 33,554,432  [b][s][h]
    unsigned short* XT = (unsigned short*)(ws + 33554432);   // 33,554,432  [b][h][s]
    unsigned short* WT = (unsigned short*)(ws + 67108864);   //  2,097,152  [h'][o]
    unsigned short* G  = (unsigned short*)(ws + 69206016);   //  8,388,608  [b][o][h]
    unsigned short* MT = (unsigned short*)(ws + 77594624);   //  8,388,608  [b][h''][h]
    // Scratch (reused serially): Gpart then MTpart, each [sp(4)][b][1024][1024]
    unsigned short* Gpart  = (unsigned short*)(ws + 85983232); // 16,777,216
    unsigned short* MTpart = (unsigned short*)(ws + 85983232); // 16,777,216
    // high-water: 102,760,448 bytes < 153,092,096 proven available

    const size_t sBH = (size_t)B_DIM * H_DIM * H_DIM;

    // 1) casts + transposes (X and W in one dispatch; z==4 = W tiles)
    cast_xw_kernel<<<dim3(H_DIM / 64, S_DIM / 64, B_DIM + 1), dim3(16, 16), 0, stream>>>(
        X, W, Xb, XT, WT);

    // 2) G_b = XT_b @ XT_b^T, full symmetric, split-K=4 (Ksub=1024, T=16).
    gemm_c8_kernel<unsigned short, 4><<<dim3(4, 4, B_DIM * 4), 512, 131072, stream>>>(
        XT, XT, Gpart, S_DIM, S_DIM, S_DIM, H_DIM,
        (size_t)H_DIM * S_DIM, (size_t)H_DIM * S_DIM, (size_t)H_DIM * H_DIM, sBH);
    reduce_cast_u16_kernel<4><<<dim3(sBH / 8 / 256), 256, 0, stream>>>(Gpart, G, sBH);

    // 3) MT_b = G_b @ WT^T, split-K=4 (Ksub=256, T=4)
    gemm_c8_kernel<unsigned short, 4><<<dim3(4, 4, B_DIM * 4), 512, 131072, stream>>>(
        G, WT, MTpart, H_DIM, H_DIM, H_DIM, H_DIM,
        (size_t)H_DIM * H_DIM, (size_t)0, (size_t)H_DIM * H_DIM, sBH);
    reduce_cast_u16_kernel<4><<<dim3(sBH / 8 / 256), 256, 0, stream>>>(MTpart, MT, sBH);

    // 4) att_b = Xb_b @ MT_b^T  [4096x1024], K=1024 (T=16), fp32 out.
    //    grid (16,4,4) = 256 blocks = 1/CU exactly.
    gemm_c8_kernel<float, 1><<<dim3(S_DIM / 256, H_DIM / 256, B_DIM), 512, 131072, stream>>>(
        Xb, MT, out, H_DIM, H_DIM, H_DIM, H_DIM,
        (size_t)S_DIM * H_DIM, (size_t)H_DIM * H_DIM, (size_t)S_DIM * H_DIM, 0);
}